// Round 10
// baseline (324.206 us; speedup 1.0000x reference)
//
#include <hip/hip_runtime.h>

// GraphSAGE 2-layer: N=100k, E=800k, 128->128(relu)->64. fp32 in/out.
// R9: gemm1 rebuilt — 8-wave blocks with CTW=2 so the B panel (64 VGPR)
// truly fits in registers (R8's CTW=4 needed 160, compiler silently
// rematerialized); perm-packed RTZ hi/lo converts (~6 ops/pair vs 14);
// k_fill fused into gemm1 (scatter hides under GEMM).
//   gemm1: g1(bf16) = x@W1l, p1(f32) = x@W1r + b1
//   agg1 : h(bf16)  = relu(mean(g1) + p1)        [h in p1's buffer]
//   gemm2: g2(bf16) = h@W2l, p2(bf16) = h@W2r + b2
//   agg2 : out(f32) = mean(g2) + p2

#define CH 128

typedef short short8 __attribute__((ext_vector_type(8)));
typedef float f32x4 __attribute__((ext_vector_type(4)));
typedef unsigned int uint32x4 __attribute__((ext_vector_type(4)));

__device__ __forceinline__ short f2bf(float x) {        // RNE fp32->bf16
    unsigned u = __float_as_uint(x);
    unsigned r = u + 0x7FFFu + ((u >> 16) & 1u);
    return (short)(r >> 16);
}
__device__ __forceinline__ float b2f(short s) {
    return __uint_as_float(((unsigned)(unsigned short)s) << 16);
}

// packed split of a float pair: hi = RTZ bf16 pair (one v_perm), lo = RTZ of
// residuals (2 and + 2 sub + 1 perm). word = (bf(x1)<<16)|bf(x0).
__device__ __forceinline__ void cvt_pair(float x0, float x1, unsigned& hi, unsigned& lo) {
    const unsigned u0 = __float_as_uint(x0), u1 = __float_as_uint(x1);
    hi = __builtin_amdgcn_perm(u1, u0, 0x07060302u);
    const float r0 = x0 - __uint_as_float(u0 & 0xFFFF0000u);
    const float r1 = x1 - __uint_as_float(u1 & 0xFFFF0000u);
    lo = __builtin_amdgcn_perm(__float_as_uint(r1), __float_as_uint(r0), 0x07060302u);
}

// ---------------- CSR build ----------------

__global__ __launch_bounds__(256) void k_zero(int* __restrict__ cnt, int N) {
    int i = blockIdx.x * blockDim.x + threadIdx.x;
    if (i <= N) cnt[i] = 0;            // cnt[N] doubles as the alloc counter
}

// B-frag pack: idx = ((ct*4 + kt)*64 + lane)*8 + j ; c = ct*16 + (lane&15),
// k = kt*32 + (lane>>4)*8 + j ; cols = [Wa | Wb] (C2 each).
__device__ __forceinline__ void pack_one(const float* __restrict__ Wa, const float* __restrict__ Wb,
                                         int C2, short* __restrict__ hi, short* __restrict__ lo, int idx) {
    int j    = idx & 7;
    int lane = (idx >> 3) & 63;
    int kt   = (idx >> 9) & 3;
    int ct   = idx >> 11;
    int c = ct * 16 + (lane & 15);
    int k = kt * 32 + (lane >> 4) * 8 + j;
    float w = (c < C2) ? Wa[k * C2 + c] : Wb[k * C2 + (c - C2)];
    short h = f2bf(w);
    hi[idx] = h;
    lo[idx] = f2bf(w - b2f(h));
}

// count degrees (capturing per-edge rank) + pack W panels
__global__ __launch_bounds__(256) void k_count_pack(const int* __restrict__ dst, int E, int* __restrict__ cnt,
                                                    int* __restrict__ rank,
                                                    const float* __restrict__ W1l, const float* __restrict__ W1r,
                                                    const float* __restrict__ W2l, const float* __restrict__ W2r,
                                                    short* __restrict__ pw1h, short* __restrict__ pw1l,
                                                    short* __restrict__ pw2h, short* __restrict__ pw2l) {
    int gid = blockIdx.x * 256 + threadIdx.x;
    if (gid < 32768)      pack_one(W1l, W1r, 128, pw1h, pw1l, gid);
    else if (gid < 49152) pack_one(W2l, W2r, 64, pw2h, pw2l, gid - 32768);
    int stride = gridDim.x * blockDim.x;
    for (int e = gid; e < E; e += stride)
        rank[e] = atomicAdd(&cnt[dst[e]], 1);   // rank = slot within dst segment
}

__global__ __launch_bounds__(256) void k_alloc(const int* __restrict__ cnt, int* __restrict__ start,
                                               int* __restrict__ counter, int N) {
    int n = blockIdx.x * blockDim.x + threadIdx.x;
    int lane = threadIdx.x & 63;
    int d = (n < N) ? cnt[n] : 0;
    int x = d;
#pragma unroll
    for (int o = 1; o < 64; o <<= 1) {
        int y = __shfl_up(x, o);
        if (lane >= o) x += y;
    }
    int total = __shfl(x, 63);
    int base = 0;
    if (lane == 63) base = atomicAdd(counter, total);
    base = __shfl(base, 63);
    int st = base + x - d;
    if (n < N) start[n] = st;
}

// ---------------- fused: atomic-free CSR fill + gemm1 ----------------
// 8 waves/block (512 thr). Wave wv holds B col-tiles {wv*2, wv*2+1} in regs
// (64 VGPR) — truly persistent. Each block first scatters its edge slice
// (hides under GEMM of other blocks), then grid-strides 16-row chunks.
__global__ __launch_bounds__(512, 2) void k_fill_gemm1(const int* __restrict__ src, const int* __restrict__ dst,
                                                       const int* __restrict__ rank, const int* __restrict__ start,
                                                       int E, int* __restrict__ eidx,
                                                       const float* __restrict__ X,
                                                       const short* __restrict__ pHi,
                                                       const short* __restrict__ pLo,
                                                       const float* __restrict__ bias,
                                                       unsigned short* __restrict__ Ga,
                                                       float* __restrict__ Pb,
                                                       int N, int nchunks) {
    constexpr int CTW = 2, CTA = 8;
    const int lane  = threadIdx.x & 63;
    const int wv    = threadIdx.x >> 6;        // 0..7
    const int ncol  = lane & 15;
    const int rbase = (lane >> 4) * 4;
    const int koff  = (lane >> 4) * 8;

    // persistent B fragments + bias
    short8 Bh[CTW][4], Bl[CTW][4];
    float bv[CTW];
#pragma unroll
    for (int c = 0; c < CTW; ++c) {
        const int ct = wv * CTW + c;
        bv[c] = (ct >= CTA) ? bias[(ct - CTA) * 16 + ncol] : 0.f;
#pragma unroll
        for (int kt = 0; kt < 4; ++kt) {
            const size_t fo = ((size_t)(ct * 4 + kt) * 64 + lane) * 8;
            Bh[c][kt] = *(const short8*)(pHi + fo);
            Bl[c][kt] = *(const short8*)(pLo + fo);
        }
    }

    // CSR fill slice (atomic-free scatter; ~3 edges/thread)
    {
        const int stride = gridDim.x * 512;
        for (int e = blockIdx.x * 512 + threadIdx.x; e < E; e += stride)
            eidx[start[dst[e]] + rank[e]] = src[e];
    }

    // GEMM chunks
#pragma unroll 1
    for (int chunk = blockIdx.x; chunk < nchunks; chunk += gridDim.x) {
        const int n0 = chunk * 16;
        int arow = n0 + ncol;
        if (arow >= N) arow = N - 1;           // clamped load, stores predicated
        const float* __restrict__ xr = X + (size_t)arow * CH + koff;

        float4 ra[8];                          // raw A prefetch: all 8 loads in flight
#pragma unroll
        for (int kt = 0; kt < 4; ++kt) {
            ra[2 * kt]     = *(const float4*)(xr + kt * 32);
            ra[2 * kt + 1] = *(const float4*)(xr + kt * 32 + 4);
        }

        f32x4 accA[CTW], accB[CTW];
#pragma unroll
        for (int c = 0; c < CTW; ++c) {
            accA[c][0] = bv[c]; accA[c][1] = bv[c]; accA[c][2] = bv[c]; accA[c][3] = bv[c];
            accB[c][0] = 0.f;   accB[c][1] = 0.f;   accB[c][2] = 0.f;   accB[c][3] = 0.f;
        }

#pragma unroll
        for (int kt = 0; kt < 4; ++kt) {
            union { uint32x4 u; short8 s; } H, L;
#pragma unroll
            for (int p = 0; p < 2; ++p) {
                const float4 a = ra[2 * kt + p];
                unsigned h0, l0, h1, l1;
                cvt_pair(a.x, a.y, h0, l0);
                cvt_pair(a.z, a.w, h1, l1);
                H.u[2 * p] = h0; H.u[2 * p + 1] = h1;
                L.u[2 * p] = l0; L.u[2 * p + 1] = l1;
            }
#pragma unroll
            for (int c = 0; c < CTW; ++c) {
                accA[c] = __builtin_amdgcn_mfma_f32_16x16x32_bf16(H.s, Bh[c][kt], accA[c], 0, 0, 0);
                accB[c] = __builtin_amdgcn_mfma_f32_16x16x32_bf16(L.s, Bh[c][kt], accB[c], 0, 0, 0);
                accB[c] = __builtin_amdgcn_mfma_f32_16x16x32_bf16(H.s, Bl[c][kt], accB[c], 0, 0, 0);
            }
        }

        const int mrow = n0 + rbase;
#pragma unroll
        for (int c = 0; c < CTW; ++c) {
            const int ct = wv * CTW + c;
            if (ct < CTA) {
                const int col = ct * 16 + ncol;
#pragma unroll
                for (int r = 0; r < 4; ++r) {
                    const int n = mrow + r;
                    if (n < N)
                        Ga[(size_t)n * 128 + col] = (unsigned short)f2bf(accA[c][r] + accB[c][r]);
                }
            } else {
                const int col = (ct - CTA) * 16 + ncol;
#pragma unroll
                for (int r = 0; r < 4; ++r) {
                    const int n = mrow + r;
                    if (n < N)
                        Pb[(size_t)n * 128 + col] = accA[c][r] + accB[c][r];
                }
            }
        }
    }
}

// ---------------- gemm2: persistent-B, EXACT bf16 A (h), 2-term MFMA ----------------
// A rows read from h (bf16, row stride 256 ushorts). g2/p2 outputs bf16.
__global__ __launch_bounds__(256, 4) void k_gemm2(const unsigned short* __restrict__ H,
                                                  const short* __restrict__ pHi,
                                                  const short* __restrict__ pLo,
                                                  const float* __restrict__ bias,
                                                  unsigned short* __restrict__ Ga,
                                                  unsigned short* __restrict__ Pb,
                                                  int N, int nchunks) {
    constexpr int CTW = 2, CTA = 4;
    const int lane  = threadIdx.x & 63;
    const int wv    = threadIdx.x >> 6;
    const int ncol  = lane & 15;
    const int rbase = (lane >> 4) * 4;
    const int koff  = (lane >> 4) * 8;

    short8 Bh[CTW][4], Bl[CTW][4];
    float bv[CTW];
#pragma unroll
    for (int c = 0; c < CTW; ++c) {
        const int ct = wv * CTW + c;
        bv[c] = (ct >= CTA) ? bias[(ct - CTA) * 16 + ncol] : 0.f;
#pragma unroll
        for (int kt = 0; kt < 4; ++kt) {
            const size_t fo = ((size_t)(ct * 4 + kt) * 64 + lane) * 8;
            Bh[c][kt] = *(const short8*)(pHi + fo);
            Bl[c][kt] = *(const short8*)(pLo + fo);
        }
    }

#pragma unroll 1
    for (int chunk = blockIdx.x; chunk < nchunks; chunk += gridDim.x) {
        const int n0 = chunk * 16;
        short8 Ah[4];
        {
            int arow = n0 + ncol;
            if (arow >= N) arow = N - 1;
            const unsigned short* __restrict__ hr = H + (size_t)arow * 256 + koff;
#pragma unroll
            for (int kt = 0; kt < 4; ++kt)
                Ah[kt] = *(const short8*)(hr + kt * 32);
        }

        const int mrow = n0 + rbase;
#pragma unroll
        for (int c = 0; c < CTW; ++c) {
            const int ct = wv * CTW + c;
            f32x4 accA, accB;
            accA[0] = bv[c]; accA[1] = bv[c]; accA[2] = bv[c]; accA[3] = bv[c];
            accB[0] = 0.f;   accB[1] = 0.f;   accB[2] = 0.f;   accB[3] = 0.f;
#pragma unroll
            for (int kt = 0; kt < 4; ++kt) {
                accA = __builtin_amdgcn_mfma_f32_16x16x32_bf16(Ah[kt], Bh[c][kt], accA, 0, 0, 0);
                accB = __builtin_amdgcn_mfma_f32_16x16x32_bf16(Ah[kt], Bl[c][kt], accB, 0, 0, 0);
            }
            unsigned short* __restrict__ O = (ct < CTA) ? Ga : Pb;
            const int col = ((ct < CTA) ? ct : ct - CTA) * 16 + ncol;
#pragma unroll
            for (int r = 0; r < 4; ++r) {
                const int n = mrow + r;
                if (n < N)
                    O[(size_t)n * 64 + col] = (unsigned short)f2bf(accA[r] + accB[r]);
            }
        }
    }
}

// ---------------- aggregation: out = [relu](mean_gather(Gbf16) + P) ----------------
// PSTRIDE/OSTRIDE in elements of their storage type.
template <int CHW, bool RELU, bool PBF16, bool OBF16, int PSTRIDE, int OSTRIDE>
__global__ __launch_bounds__(256) void k_agg(const unsigned short* __restrict__ G,
                                             const void* __restrict__ Pv,
                                             const int* __restrict__ start,
                                             const int* __restrict__ cnt,
                                             const int* __restrict__ eidx,
                                             void* __restrict__ outv, int N) {
    constexpr int LPN = CHW / 8;       // lanes per node: 16 / 8
    constexpr int NPB = 256 / LPN;     // nodes per block: 16 / 32
    const int g = threadIdx.x / LPN;
    const int l = threadIdx.x % LPN;
    const int n = blockIdx.x * NPB + g;
    if (n >= N) return;
    const int s0 = start[n];
    const int d  = cnt[n];
    const int* __restrict__ ep = eidx + s0;
    const int co = l * 8;

    float acc[8];
#pragma unroll
    for (int j = 0; j < 8; ++j) acc[j] = 0.f;

    int i = 0;
    for (; i + 4 <= d; i += 4) {
        const int e0 = ep[i], e1 = ep[i + 1], e2 = ep[i + 2], e3 = ep[i + 3];
        const short8 v0 = *(const short8*)&G[(size_t)e0 * CHW + co];
        const short8 v1 = *(const short8*)&G[(size_t)e1 * CHW + co];
        const short8 v2 = *(const short8*)&G[(size_t)e2 * CHW + co];
        const short8 v3 = *(const short8*)&G[(size_t)e3 * CHW + co];
#pragma unroll
        for (int j = 0; j < 8; ++j)
            acc[j] += (b2f(v0[j]) + b2f(v1[j])) + (b2f(v2[j]) + b2f(v3[j]));
    }
    for (; i < d; ++i) {
        const short8 v = *(const short8*)&G[(size_t)ep[i] * CHW + co];
#pragma unroll
        for (int j = 0; j < 8; ++j) acc[j] += b2f(v[j]);
    }

    const float sc = 1.0f / (float)(d > 0 ? d : 1);
    float r[8];
    if (PBF16) {
        const short8 pp = *(const short8*)((const unsigned short*)Pv + (size_t)n * PSTRIDE + co);
#pragma unroll
        for (int j = 0; j < 8; ++j) r[j] = fmaf(acc[j], sc, b2f(pp[j]));
    } else {
        const float* __restrict__ P = (const float*)Pv;
        const float4 p0 = *(const float4*)&P[(size_t)n * PSTRIDE + co];
        const float4 p1 = *(const float4*)&P[(size_t)n * PSTRIDE + co + 4];
        r[0] = fmaf(acc[0], sc, p0.x); r[1] = fmaf(acc[1], sc, p0.y);
        r[2] = fmaf(acc[2], sc, p0.z); r[3] = fmaf(acc[3], sc, p0.w);
        r[4] = fmaf(acc[4], sc, p1.x); r[5] = fmaf(acc[5], sc, p1.y);
        r[6] = fmaf(acc[6], sc, p1.z); r[7] = fmaf(acc[7], sc, p1.w);
    }
    if (RELU) {
#pragma unroll
        for (int j = 0; j < 8; ++j) r[j] = fmaxf(r[j], 0.f);
    }
    if (OBF16) {
        // single 16B store per lane; value depends on ALL p-loads -> compiler's
        // s_waitcnt completes every lane's p-load before any overlapping store.
        short8 hv;
#pragma unroll
        for (int j = 0; j < 8; ++j) hv[j] = f2bf(r[j]);
        *(short8*)((unsigned short*)outv + (size_t)n * OSTRIDE + co) = hv;
    } else {
        float4 r0, r1;
        r0.x = r[0]; r0.y = r[1]; r0.z = r[2]; r0.w = r[3];
        r1.x = r[4]; r1.y = r[5]; r1.z = r[6]; r1.w = r[7];
        *(float4*)((float*)outv + (size_t)n * OSTRIDE + co) = r0;
        *(float4*)((float*)outv + (size_t)n * OSTRIDE + co + 4) = r1;
    }
}

// ---------------- launch ----------------

extern "C" void kernel_launch(void* const* d_in, const int* in_sizes, int n_in,
                              void* d_out, int out_size, void* d_ws, size_t ws_size,
                              hipStream_t stream) {
    const float* x   = (const float*)d_in[0];
    const int*   ei  = (const int*)d_in[1];
    const float* W1l = (const float*)d_in[2];
    const float* W1r = (const float*)d_in[3];
    const float* b1  = (const float*)d_in[4];
    const float* W2l = (const float*)d_in[5];
    const float* W2r = (const float*)d_in[6];
    const float* b2  = (const float*)d_in[7];
    float* out = (float*)d_out;

    const int N = in_sizes[0] / CH;
    const int E = in_sizes[1] / 2;
    const int* src = ei;
    const int* dst = ei + E;

    // workspace carve
    char* w = (char*)d_ws;
    size_t o = 0;
    int* cnt     = (int*)(w + o); o += ((size_t)N + 4) * 4;   // cnt[N] = alloc counter
    int* start   = (int*)(w + o); o += (size_t)N * 4;
    int* rank    = (int*)(w + o); o += (size_t)E * 4;         // per-edge segment rank
    int* eidx    = (int*)(w + o); o += (size_t)E * 4;
    short* pw1h  = (short*)(w + o); o += 32768 * 2;
    short* pw1l  = (short*)(w + o); o += 32768 * 2;
    short* pw2h  = (short*)(w + o); o += 16384 * 2;
    short* pw2l  = (short*)(w + o); o += 16384 * 2;
    unsigned short* bufG = (unsigned short*)(w + o); o += (size_t)N * CH * 2;  // g1 / g2 (bf16)
    float* bufP1 = (float*)(w + o); o += (size_t)N * CH * 4;  // p1 fp32; h bf16 embedded (row=512B)
    unsigned short* bufP2 = (unsigned short*)(w + o); o += (size_t)N * 64 * 2; // p2 bf16
    (void)ws_size; (void)n_in; (void)out_size;

    int* counter = cnt + N;
    unsigned short* g1 = bufG;
    float* p1 = bufP1;
    unsigned short* h = (unsigned short*)bufP1;   // row stride 256 ushorts (512 B)
    unsigned short* g2 = bufG;                    // g1 dead after agg1
    unsigned short* p2 = bufP2;

    const int TB = 256;
    const int zb = (N + TB) / TB;           // covers cnt[0..N]
    const int nchunks = (N + 15) / 16;

    hipLaunchKernelGGL(k_zero, dim3(zb), dim3(TB), 0, stream, cnt, N);
    hipLaunchKernelGGL(k_count_pack, dim3(2048), dim3(TB), 0, stream, dst, E, cnt, rank,
                       W1l, W1r, W2l, W2r, pw1h, pw1l, pw2h, pw2l);
    hipLaunchKernelGGL(k_alloc, dim3((N + TB - 1) / TB), dim3(TB), 0, stream,
                       cnt, start, counter, N);

    // layer 1 (fill fused into gemm1; both complete before agg1)
    hipLaunchKernelGGL(k_fill_gemm1, dim3(512), dim3(512), 0, stream,
                       src, dst, rank, start, E, eidx,
                       x, pw1h, pw1l, b1, g1, p1, N, nchunks);
    hipLaunchKernelGGL((k_agg<128, true, false, true, 128, 256>), dim3((N + 15) / 16), dim3(TB), 0, stream,
                       g1, p1, start, cnt, eidx, h, N);
    // layer 2
    hipLaunchKernelGGL(k_gemm2, dim3(1024), dim3(TB), 0, stream,
                       h, pw2h, pw2l, b2, g2, p2, N, nchunks);
    hipLaunchKernelGGL((k_agg<64, false, true, false, 64, 64>), dim3((N + 31) / 32), dim3(TB), 0, stream,
                       g2, p2, start, cnt, eidx, out, N);
}